// Round 10
// baseline (1101.987 us; speedup 1.0000x reference)
//
#include <hip/hip_runtime.h>

#define N_LIG 16384
#define M_POC 32768
#define N_TOT (N_LIG + M_POC)           // 49152
#define E_LIG 163840
#define E_POC 327680
#define E_CROSS (N_LIG * 8)             // 131072
#define E_TOT (E_LIG + E_POC + E_CROSS) // 622592
#define TE 16                           // nodes per wave tile (k_node)

typedef __bf16 bf16_t;
typedef bf16_t bf16x8 __attribute__((ext_vector_type(8)));
typedef bf16_t bf16x4 __attribute__((ext_vector_type(4)));
typedef float f32x4 __attribute__((ext_vector_type(4)));

// k_edge LDS: ONE wave-private mT buffer (32 edge rows, stride 72 bf16)
#define SM 72
#define EDGE_WAVE_BYTES (32 * SM * 2)   // 4608 B/wave -> 18432 B/block; x8 blocks = 147 KB/CU OK

// fast transcendentals (v_rcp_f32; rel err ~1e-7 << bf16 rounding)
__device__ __forceinline__ float fast_rcp(float x) { return __builtin_amdgcn_rcpf(x); }
__device__ __forceinline__ float silu_f(float v) {
    return v * fast_rcp(1.0f + __expf(-v));
}
__device__ __forceinline__ float tanh_f(float v) {
    float a = fabsf(v);
    float t = __expf(-2.0f * a);
    float r = (1.0f - t) * fast_rcp(1.0f + t);
    return copysignf(r, v);
}

__device__ __forceinline__ void atomic_add_f32(float* p, float v) {
    __hip_atomic_fetch_add(p, v, __ATOMIC_RELAXED, __HIP_MEMORY_SCOPE_AGENT);
}

// wave-level LDS fence (all LDS regions are wave-private)
__device__ __forceinline__ void lds_fence() {
    asm volatile("s_waitcnt lgkmcnt(0)" ::: "memory");
}

// ---------------- setup kernels ----------------

// builds src/dst, histograms dst, AND packs attr fragments (one pass over edges)
__global__ void k_build_edges(const int* __restrict__ lig_ei, const int* __restrict__ poc_ei,
                              const int* __restrict__ cross_ei,
                              const float* __restrict__ lig_attr, const float* __restrict__ poc_attr,
                              const float* __restrict__ cross_attr,
                              int* __restrict__ srcA, int* __restrict__ dstA,
                              int* __restrict__ cnt, bf16_t* __restrict__ attrF) {
    int e = blockIdx.x * blockDim.x + threadIdx.x;
    if (e >= E_TOT) return;
    int s, d;
    const float* a; int K;
    if (e < E_LIG) {
        s = lig_ei[e];
        d = lig_ei[E_LIG + e];
        a = lig_attr + (size_t)e * 6; K = 6;
    } else if (e < E_LIG + E_POC) {
        int i = e - E_LIG;
        s = poc_ei[i] + N_LIG;
        d = poc_ei[E_POC + i] + N_LIG;
        a = poc_attr + (size_t)i * 16; K = 16;
    } else {
        int i = e - E_LIG - E_POC;
        s = cross_ei[i] + N_LIG;
        d = cross_ei[E_CROSS + i];
        a = cross_attr + (size_t)i * 16; K = 16;
    }
    srcA[e] = s;
    dstA[e] = d;
    atomicAdd(&cnt[d], 1);
    bf16_t* o = attrF + (size_t)e * 16;
    #pragma unroll
    for (int k = 0; k < 16; ++k) o[k] = (bf16_t)((k < K) ? a[k] : 0.0f);
}

// single block, 1024 threads, 48 bins per thread
__global__ __launch_bounds__(1024) void k_scan(const int* __restrict__ cnt,
                                               int* __restrict__ rowptr,
                                               int* __restrict__ cursor) {
    __shared__ int sums[1024];
    int tid = threadIdx.x;
    int local[48];
    int s = 0;
    for (int i = 0; i < 48; ++i) { local[i] = s; s += cnt[tid * 48 + i]; }
    sums[tid] = s;
    __syncthreads();
    for (int off = 1; off < 1024; off <<= 1) {
        int v = (tid >= off) ? sums[tid - off] : 0;
        __syncthreads();
        sums[tid] += v;
        __syncthreads();
    }
    int base = (tid == 0) ? 0 : sums[tid - 1];
    for (int i = 0; i < 48; ++i) {
        int v = base + local[i];
        int idx = tid * 48 + i;
        rowptr[idx] = v;
        cursor[idx] = v;
    }
    if (tid == 1023) rowptr[N_TOT] = sums[1023];
}

__global__ void k_scatter(const int* __restrict__ dstA, int* __restrict__ cursor,
                          int* __restrict__ sortedPos) {
    int e = blockIdx.x * blockDim.x + threadIdx.x;
    if (e < E_TOT) sortedPos[e] = atomicAdd(&cursor[dstA[e]], 1);
}

// ---- fused weight prep ----
// Fragment mapping (weights-as-A): frag[lane][j] = W[kbase+(lane>>4)*8+j][ft*16+(lane&15)]
// GEMM1 k-layout: 0..63 h_src, 64..127 h_dst, 128..143 folded attr, 144 dist, 145..159 zero.
#define PK_G1   (12 * 5 * 4 * 64)                     // 15360
#define PK_G23  (4 * 4 * 4 * 64)                      // 4096
#define PK_WH   (4 * 24 * 64)                         // 6144
#define PK_BEFF (12 * 64)                             // 768
#define PK_TOT  (PK_G1 + PK_G23 + PK_WH + PK_BEFF)    // 26368

__global__ void k_pack_all(const float* __restrict__ phi_e_W1, const float* __restrict__ phi_e_b1,
                           const float* __restrict__ lig_ee_W, const float* __restrict__ lig_ee_b,
                           const float* __restrict__ poc_ee_W, const float* __restrict__ poc_ee_b,
                           const float* __restrict__ cross_ee_W, const float* __restrict__ cross_ee_b,
                           const float* __restrict__ phi_e_W2, const float* __restrict__ phi_x_W1,
                           const float* __restrict__ phi_h_W1, const float* __restrict__ phi_h_W2,
                           bf16_t* __restrict__ Bg1, bf16_t* __restrict__ Bg23,
                           bf16_t* __restrict__ WhP, float* __restrict__ beff) {
    int tid = blockIdx.x * blockDim.x + threadIdx.x;
    if (tid < PK_G1) {
        int lt = tid / 1280;
        int rem = tid - lt * 1280;
        int c = rem >> 8;
        int ft = (rem >> 6) & 3;
        int lane = rem & 63;
        int l = lt / 3, t = lt % 3;
        const float* W1l = phi_e_W1 + l * 193 * 64;
        const float* We; int K;
        if (t == 0) { We = lig_ee_W; K = 6; }
        else if (t == 1) { We = poc_ee_W; K = 16; }
        else { We = cross_ee_W; K = 16; }
        int col = ft * 16 + (lane & 15);
        int k0 = c * 32 + (lane >> 4) * 8;
        #pragma unroll
        for (int j = 0; j < 8; ++j) {
            int row = k0 + j;
            float v = 0.0f;
            if (row < 128) v = W1l[row * 64 + col];
            else if (row < 144) {
                int kk = row - 128;
                if (kk < K) {
                    float a = 0.0f;
                    for (int q = 0; q < 64; ++q) a = fmaf(We[kk * 64 + q], W1l[(129 + q) * 64 + col], a);
                    v = a;
                }
            } else if (row == 144) {
                v = W1l[128 * 64 + col];   // dist row
            }
            Bg1[(size_t)tid * 8 + j] = (bf16_t)v;
        }
    } else if (tid < PK_G1 + PK_G23) {
        int u = tid - PK_G1;
        int lane = u & 63;
        int ft = (u >> 6) & 3;
        int c = (u >> 8) & 3;
        int l = u >> 10;
        const float* W = (c < 2) ? (phi_e_W2 + l * 4096) : (phi_x_W1 + l * 4096);
        int kb = (c & 1) * 32;
        int col = ft * 16 + (lane & 15);
        int k0 = kb + (lane >> 4) * 8;
        #pragma unroll
        for (int j = 0; j < 8; ++j)
            Bg23[(size_t)u * 8 + j] = (bf16_t)W[(k0 + j) * 64 + col];
    } else if (tid < PK_G1 + PK_G23 + PK_WH) {
        int u = tid - PK_G1 - PK_G23;
        int lane = u & 63;
        int frag = (u >> 6) % 24;
        int l = (u >> 6) / 24;
        const float* W; int kc, ft;
        if (frag < 16) { W = phi_h_W1 + l * 128 * 64; kc = frag >> 2; ft = frag & 3; }
        else           { W = phi_h_W2 + l * 64 * 64;  kc = (frag - 16) >> 2; ft = (frag - 16) & 3; }
        int col = ft * 16 + (lane & 15);
        int k0 = kc * 32 + (lane >> 4) * 8;
        #pragma unroll
        for (int j = 0; j < 8; ++j)
            WhP[(size_t)u * 8 + j] = (bf16_t)W[(k0 + j) * 64 + col];
    } else if (tid < PK_TOT) {
        int u = tid - PK_G1 - PK_G23 - PK_WH;
        int j = u & 63;
        int lt = u >> 6;
        int l = lt / 3, t = lt % 3;
        const float* W1l = phi_e_W1 + l * 193 * 64;
        const float* Be = (t == 0) ? lig_ee_b : ((t == 1) ? poc_ee_b : cross_ee_b);
        float v = phi_e_b1[l * 64 + j];
        for (int q = 0; q < 64; ++q) v = fmaf(Be[q], W1l[(129 + q) * 64 + j], v);
        beff[u] = v;
    }
}

__global__ void k_embed(const float* __restrict__ lig_x, const float* __restrict__ lig_h,
                        const float* __restrict__ poc_x, const float* __restrict__ poc_h,
                        const float* __restrict__ t,
                        const float* __restrict__ ligW, const float* __restrict__ ligB,
                        const float* __restrict__ pocW, const float* __restrict__ pocB,
                        float* __restrict__ h, bf16_t* __restrict__ hB, float* __restrict__ x4) {
    int gid = blockIdx.x * blockDim.x + threadIdx.x;
    int n = gid >> 6;
    int lane = gid & 63;
    if (n >= N_TOT) return;
    float a;
    if (n < N_LIG) {
        a = ligB[lane];
        #pragma unroll
        for (int k = 0; k < 17; ++k) a = fmaf(lig_h[n * 17 + k], ligW[k * 64 + lane], a);
        a = fmaf(t[0], ligW[17 * 64 + lane], a);
        if (lane < 4) x4[n * 4 + lane] = (lane < 3) ? lig_x[n * 3 + lane] : 0.0f;
    } else {
        int p = n - N_LIG;
        a = pocB[lane];
        #pragma unroll
        for (int k = 0; k < 29; ++k) a = fmaf(poc_h[p * 29 + k], pocW[k * 64 + lane], a);
        if (lane < 4) x4[n * 4 + lane] = (lane < 3) ? poc_x[p * 3 + lane] : 0.0f;
    }
    h[n * 64 + lane] = a;
    hB[n * 64 + lane] = (bf16_t)a;
}

// ---------------- per-layer MFMA edge kernel: 32 edges/wave, register extras ----------------
// VGPR=60 (measured R9) <= 64 -> 8 waves/SIMD allowed; LDS 18.4KB*8 = 147KB <= 160KB.
__global__ __launch_bounds__(256, 8) void k_edge_mfma(
    const bf16_t* __restrict__ hB, const float* __restrict__ x4,
    const int* __restrict__ srcA, const int* __restrict__ dstA,
    const int* __restrict__ sortedPos,
    const bf16_t* __restrict__ attrF,
    const bf16_t* __restrict__ Bg1L,   // + t*5*4*512 inside
    const float* __restrict__ beffL,   // + t*64 inside
    const bf16_t* __restrict__ Bg23L,
    const float* __restrict__ b2, const float* __restrict__ bx1,
    const float* __restrict__ Wx2, const float* __restrict__ bx2,
    bf16_t* __restrict__ mBuf, float* __restrict__ coord_agg) {
    __shared__ __align__(16) char lds[4 * EDGE_WAVE_BYTES];
    const int lane = threadIdx.x & 63;
    const int wave = threadIdx.x >> 6;
    bf16_t* mT = (bf16_t*)(lds + wave * EDGE_WAVE_BYTES);
    const int base = (blockIdx.x * 4 + wave) * 32;

    // edge type (tile-uniform) — only selects weight pack
    int tt;
    if (base < E_LIG) tt = 0;
    else if (base < E_LIG + E_POC) tt = 1;
    else tt = 2;

    const int edge = lane & 15;
    const int kgrp = lane >> 4;
    const int mrow0 = kgrp * 4;
    const int e0 = base + edge;
    const int e1 = base + 16 + edge;
    const int sv0 = srcA[e0], sv1 = srcA[e1];
    const int dv0 = dstA[e0], dv1 = dstA[e1];
    const int sp0 = sortedPos[e0], sp1 = sortedPos[e1];

    // ---- h B-fragments: 8 direct 16B gathers (layout-exact, all independent) ----
    bf16x8 hs0a = *(const bf16x8*)(hB + (size_t)sv0 * 64 + kgrp * 8);
    bf16x8 hs0b = *(const bf16x8*)(hB + (size_t)sv0 * 64 + 32 + kgrp * 8);
    bf16x8 hd0a = *(const bf16x8*)(hB + (size_t)dv0 * 64 + kgrp * 8);
    bf16x8 hd0b = *(const bf16x8*)(hB + (size_t)dv0 * 64 + 32 + kgrp * 8);
    bf16x8 hs1a = *(const bf16x8*)(hB + (size_t)sv1 * 64 + kgrp * 8);
    bf16x8 hs1b = *(const bf16x8*)(hB + (size_t)sv1 * 64 + 32 + kgrp * 8);
    bf16x8 hd1a = *(const bf16x8*)(hB + (size_t)dv1 * 64 + kgrp * 8);
    bf16x8 hd1b = *(const bf16x8*)(hB + (size_t)dv1 * 64 + 32 + kgrp * 8);

    // ---- extras B-fragments (k 128..159): prepacked attr (kgrp<2) + dist (kgrp==2) ----
    const bf16_t Z = (bf16_t)0.0f;
    bf16x8 ex0 = {Z, Z, Z, Z, Z, Z, Z, Z};
    bf16x8 ex1 = {Z, Z, Z, Z, Z, Z, Z, Z};
    float d0s0 = 0.f, d1s0 = 0.f, d2s0 = 0.f;   // diffs (held on kgrp==2 lanes)
    float d0s1 = 0.f, d1s1 = 0.f, d2s1 = 0.f;
    if (kgrp < 2) {
        ex0 = *(const bf16x8*)(attrF + (size_t)e0 * 16 + kgrp * 8);
        ex1 = *(const bf16x8*)(attrF + (size_t)e1 * 16 + kgrp * 8);
    } else if (kgrp == 2) {
        float4 xs0 = *(const float4*)(x4 + (size_t)sv0 * 4);
        float4 xd0 = *(const float4*)(x4 + (size_t)dv0 * 4);
        float4 xs1 = *(const float4*)(x4 + (size_t)sv1 * 4);
        float4 xd1 = *(const float4*)(x4 + (size_t)dv1 * 4);
        d0s0 = xs0.x - xd0.x; d1s0 = xs0.y - xd0.y; d2s0 = xs0.z - xd0.z;
        d0s1 = xs1.x - xd1.x; d1s1 = xs1.y - xd1.y; d2s1 = xs1.z - xd1.z;
        float dist0 = (d0s0 * d0s0 + d1s0 * d1s0 + d2s0 * d2s0) * 0.01f;
        float dist1 = (d0s1 * d0s1 + d1s1 * d1s1 + d2s1 * d2s1) * 0.01f;
        ex0[0] = (bf16_t)dist0;
        ex1[0] = (bf16_t)dist1;
    }

    // ---- GEMM1: 5 kc x 4 ft x 2 sub-tiles (each weight frag feeds 2 MFMAs) ----
    const bf16_t* Bg1 = Bg1L + (size_t)tt * 5 * 4 * 512;
    const float* beff = beffL + tt * 64;
    f32x4 acc0[4], acc1[4];
    #pragma unroll
    for (int ft = 0; ft < 4; ++ft) {
        float4 bv = *(const float4*)(beff + ft * 16 + mrow0);
        acc0[ft] = (f32x4){bv.x, bv.y, bv.z, bv.w};
        acc1[ft] = acc0[ft];
    }
    bf16x8 bdat0[5] = {hs0a, hs0b, hd0a, hd0b, ex0};
    bf16x8 bdat1[5] = {hs1a, hs1b, hd1a, hd1b, ex1};
    #pragma unroll
    for (int c = 0; c < 5; ++c) {
        #pragma unroll
        for (int ft = 0; ft < 4; ++ft) {
            bf16x8 wfr = *(const bf16x8*)(Bg1 + ((size_t)(c * 4 + ft) * 64 + lane) * 8);
            acc0[ft] = __builtin_amdgcn_mfma_f32_16x16x32_bf16(wfr, bdat0[c], acc0[ft], 0, 0, 0);
            acc1[ft] = __builtin_amdgcn_mfma_f32_16x16x32_bf16(wfr, bdat1[c], acc1[ft], 0, 0, 0);
        }
    }
    // epilogue: lane's 4 accs = 4 consecutive feats of its edge -> packed b64 writes
    #pragma unroll
    for (int ft = 0; ft < 4; ++ft) {
        bf16x4 v0 = {(bf16_t)silu_f(acc0[ft][0]), (bf16_t)silu_f(acc0[ft][1]),
                     (bf16_t)silu_f(acc0[ft][2]), (bf16_t)silu_f(acc0[ft][3])};
        bf16x4 v1 = {(bf16_t)silu_f(acc1[ft][0]), (bf16_t)silu_f(acc1[ft][1]),
                     (bf16_t)silu_f(acc1[ft][2]), (bf16_t)silu_f(acc1[ft][3])};
        *(bf16x4*)(mT + edge * SM + ft * 16 + mrow0) = v0;
        *(bf16x4*)(mT + (16 + edge) * SM + ft * 16 + mrow0) = v1;
    }
    lds_fence();

    // ---- GEMM2: m = silu(m1 @ W2 + b2) ----
    f32x4 acc20[4], acc21[4];
    #pragma unroll
    for (int ft = 0; ft < 4; ++ft) {
        float4 bv = *(const float4*)(b2 + ft * 16 + mrow0);
        acc20[ft] = (f32x4){bv.x, bv.y, bv.z, bv.w};
        acc21[ft] = acc20[ft];
    }
    bf16x8 m10[2], m11[2];
    #pragma unroll
    for (int c = 0; c < 2; ++c) {
        m10[c] = *(const bf16x8*)(mT + edge * SM + c * 32 + kgrp * 8);
        m11[c] = *(const bf16x8*)(mT + (16 + edge) * SM + c * 32 + kgrp * 8);
    }
    #pragma unroll
    for (int c = 0; c < 2; ++c) {
        #pragma unroll
        for (int ft = 0; ft < 4; ++ft) {
            bf16x8 wfr = *(const bf16x8*)(Bg23L + ((size_t)(c * 4 + ft) * 64 + lane) * 8);
            acc20[ft] = __builtin_amdgcn_mfma_f32_16x16x32_bf16(wfr, m10[c], acc20[ft], 0, 0, 0);
            acc21[ft] = __builtin_amdgcn_mfma_f32_16x16x32_bf16(wfr, m11[c], acc21[ft], 0, 0, 0);
        }
    }
    lds_fence();   // m1 reads drained before overwrite
    #pragma unroll
    for (int ft = 0; ft < 4; ++ft) {
        bf16x4 v0 = {(bf16_t)silu_f(acc20[ft][0]), (bf16_t)silu_f(acc20[ft][1]),
                     (bf16_t)silu_f(acc20[ft][2]), (bf16_t)silu_f(acc20[ft][3])};
        bf16x4 v1 = {(bf16_t)silu_f(acc21[ft][0]), (bf16_t)silu_f(acc21[ft][1]),
                     (bf16_t)silu_f(acc21[ft][2]), (bf16_t)silu_f(acc21[ft][3])};
        *(bf16x4*)(mT + edge * SM + ft * 16 + mrow0) = v0;
        *(bf16x4*)(mT + (16 + edge) * SM + ft * 16 + mrow0) = v1;
    }
    lds_fence();

    // ---- GEMM3 B-frags from LDS; the same reads feed the mBuf store (b128 x4) ----
    bf16x8 g0[2], g1[2];
    #pragma unroll
    for (int c = 0; c < 2; ++c) {
        g0[c] = *(const bf16x8*)(mT + edge * SM + c * 32 + kgrp * 8);
        g1[c] = *(const bf16x8*)(mT + (16 + edge) * SM + c * 32 + kgrp * 8);
        *(bf16x8*)(mBuf + (size_t)sp0 * 64 + c * 32 + kgrp * 8) = g0[c];
        *(bf16x8*)(mBuf + (size_t)sp1 * 64 + c * 32 + kgrp * 8) = g1[c];
    }

    f32x4 acc30[4], acc31[4];
    #pragma unroll
    for (int ft = 0; ft < 4; ++ft) {
        float4 bv = *(const float4*)(bx1 + ft * 16 + mrow0);
        acc30[ft] = (f32x4){bv.x, bv.y, bv.z, bv.w};
        acc31[ft] = acc30[ft];
    }
    const bf16_t* Bg3 = Bg23L + (size_t)2 * 4 * 512;
    #pragma unroll
    for (int c = 0; c < 2; ++c) {
        #pragma unroll
        for (int ft = 0; ft < 4; ++ft) {
            bf16x8 wfr = *(const bf16x8*)(Bg3 + ((size_t)(c * 4 + ft) * 64 + lane) * 8);
            acc30[ft] = __builtin_amdgcn_mfma_f32_16x16x32_bf16(wfr, g0[c], acc30[ft], 0, 0, 0);
            acc31[ft] = __builtin_amdgcn_mfma_f32_16x16x32_bf16(wfr, g1[c], acc31[ft], 0, 0, 0);
        }
    }

    // ---- cw = tanh(silu(p) . Wx2 + bx2): per-lane partial, 2-shuffle reduce per sub-tile ----
    float s0 = 0.0f, s1 = 0.0f;
    #pragma unroll
    for (int ft = 0; ft < 4; ++ft) {
        float4 wv = *(const float4*)(Wx2 + ft * 16 + mrow0);
        s0 = fmaf(silu_f(acc30[ft][0]), wv.x, s0);
        s0 = fmaf(silu_f(acc30[ft][1]), wv.y, s0);
        s0 = fmaf(silu_f(acc30[ft][2]), wv.z, s0);
        s0 = fmaf(silu_f(acc30[ft][3]), wv.w, s0);
        s1 = fmaf(silu_f(acc31[ft][0]), wv.x, s1);
        s1 = fmaf(silu_f(acc31[ft][1]), wv.y, s1);
        s1 = fmaf(silu_f(acc31[ft][2]), wv.z, s1);
        s1 = fmaf(silu_f(acc31[ft][3]), wv.w, s1);
    }
    s0 += __shfl_xor(s0, 16, 64); s0 += __shfl_xor(s0, 32, 64);
    s1 += __shfl_xor(s1, 16, 64); s1 += __shfl_xor(s1, 32, 64);
    const float bx2v = bx2[0];
    const float cw0 = tanh_f(s0 + bx2v);
    const float cw1 = tanh_f(s1 + bx2v);

    // diffs live on kgrp==2 lanes (lane 32+edge); 3 shuffles per sub-tile + select
    float a0 = __shfl(d0s0, 32 + edge, 64);
    float a1 = __shfl(d1s0, 32 + edge, 64);
    float a2 = __shfl(d2s0, 32 + edge, 64);
    float b0 = __shfl(d0s1, 32 + edge, 64);
    float b1 = __shfl(d1s1, 32 + edge, 64);
    float b2v_ = __shfl(d2s1, 32 + edge, 64);
    if (kgrp < 3) {
        float dsel0 = (kgrp == 0) ? a0 : ((kgrp == 1) ? a1 : a2);
        float dsel1 = (kgrp == 0) ? b0 : ((kgrp == 1) ? b1 : b2v_);
        if (dv0 < N_LIG) atomic_add_f32(&coord_agg[dv0 * 3 + kgrp], dsel0 * cw0);
        if (dv1 < N_LIG) atomic_add_f32(&coord_agg[dv1 * 3 + kgrp], dsel1 * cw1);
    }
}

// ---------------- msg gather kernel: wave = 4 nodes, high occupancy streaming ----------------
__global__ __launch_bounds__(256, 8) void k_gather(
    const bf16_t* __restrict__ mBuf, const int* __restrict__ rowptr,
    bf16_t* __restrict__ msgB) {
    const int lane = threadIdx.x & 63;
    const int wave = threadIdx.x >> 6;
    const int fq = lane & 15;        // feature quad
    const int sub = lane >> 4;       // 4-way edge parallelism
    const int nbase = (blockIdx.x * 4 + wave) * 4;
    #pragma unroll
    for (int r = 0; r < 4; ++r) {
        const int n = nbase + r;
        const int s0 = rowptr[n];
        const int s1 = rowptr[n + 1];
        float a0 = 0.f, a1 = 0.f, a2 = 0.f, a3 = 0.f;
        for (int i = s0 + sub; i < s1; i += 4) {
            bf16x4 v = *(const bf16x4*)(mBuf + (size_t)i * 64 + fq * 4);
            a0 += (float)v[0]; a1 += (float)v[1]; a2 += (float)v[2]; a3 += (float)v[3];
        }
        a0 += __shfl_xor(a0, 16, 64); a1 += __shfl_xor(a1, 16, 64);
        a2 += __shfl_xor(a2, 16, 64); a3 += __shfl_xor(a3, 16, 64);
        a0 += __shfl_xor(a0, 32, 64); a1 += __shfl_xor(a1, 32, 64);
        a2 += __shfl_xor(a2, 32, 64); a3 += __shfl_xor(a3, 32, 64);
        if (lane < 16) {
            bf16x4 v = {(bf16_t)a0, (bf16_t)a1, (bf16_t)a2, (bf16_t)a3};
            *(bf16x4*)(msgB + (size_t)n * 64 + fq * 4) = v;
        }
    }
}

// ---------------- per-layer node update: MLP only (msgB already gathered) ----------------
#define NODE_WAVE_BYTES 2304   // mid, stride 72
__global__ __launch_bounds__(256, 8) void k_node(
    float* __restrict__ h, bf16_t* __restrict__ hB, float* __restrict__ x4,
    const bf16_t* __restrict__ msgB,
    float* __restrict__ coord,
    const bf16_t* __restrict__ WhL,   // 24 frags: 0..15 Wh1 (kc*4+ft), 16..23 Wh2
    const float* __restrict__ bh1, const float* __restrict__ bh2) {
    __shared__ __align__(16) char lds[4 * NODE_WAVE_BYTES];
    const int lane = threadIdx.x & 63;
    const int wave = threadIdx.x >> 6;
    bf16_t* mid = (bf16_t*)(lds + wave * NODE_WAVE_BYTES);
    const int base = (blockIdx.x * 4 + wave) * TE;

    const int node = lane & 15;
    const int kgrp = lane >> 4;
    const int mrow0 = kgrp * 4;
    const int n16 = base + node;

    // ---- GEMM1: D[feat][node] = Wh1^T . [h|msg]^T + bh1 : 4 kc x 4 ft ----
    f32x4 acc[4];
    #pragma unroll
    for (int ft = 0; ft < 4; ++ft) {
        float4 bv = *(const float4*)(bh1 + ft * 16 + mrow0);
        acc[ft] = (f32x4){bv.x, bv.y, bv.z, bv.w};
    }
    bf16x8 d0 = *(const bf16x8*)(hB + (size_t)n16 * 64 + kgrp * 8);
    bf16x8 d1 = *(const bf16x8*)(hB + (size_t)n16 * 64 + 32 + kgrp * 8);
    bf16x8 d2 = *(const bf16x8*)(msgB + (size_t)n16 * 64 + kgrp * 8);
    bf16x8 d3 = *(const bf16x8*)(msgB + (size_t)n16 * 64 + 32 + kgrp * 8);
    bf16x8 bdat[4] = {d0, d1, d2, d3};
    #pragma unroll
    for (int c = 0; c < 4; ++c) {
        #pragma unroll
        for (int ft = 0; ft < 4; ++ft) {
            bf16x8 wfr = *(const bf16x8*)(WhL + ((size_t)(c * 4 + ft) * 64 + lane) * 8);
            acc[ft] = __builtin_amdgcn_mfma_f32_16x16x32_bf16(wfr, bdat[c], acc[ft], 0, 0, 0);
        }
    }
    #pragma unroll
    for (int ft = 0; ft < 4; ++ft) {
        bf16x4 v = {(bf16_t)silu_f(acc[ft][0]), (bf16_t)silu_f(acc[ft][1]),
                    (bf16_t)silu_f(acc[ft][2]), (bf16_t)silu_f(acc[ft][3])};
        *(bf16x4*)(mid + node * SM + ft * 16 + mrow0) = v;
    }
    lds_fence();

    // ---- GEMM2: 2 kc x 4 ft ----
    f32x4 acc2[4];
    #pragma unroll
    for (int ft = 0; ft < 4; ++ft) {
        float4 bv = *(const float4*)(bh2 + ft * 16 + mrow0);
        acc2[ft] = (f32x4){bv.x, bv.y, bv.z, bv.w};
    }
    bf16x8 g0 = *(const bf16x8*)(mid + node * SM + kgrp * 8);
    bf16x8 g1 = *(const bf16x8*)(mid + node * SM + 32 + kgrp * 8);
    #pragma unroll
    for (int c = 0; c < 2; ++c) {
        bf16x8 df = (c == 0) ? g0 : g1;
        #pragma unroll
        for (int ft = 0; ft < 4; ++ft) {
            bf16x8 wfr = *(const bf16x8*)(WhL + ((size_t)(16 + c * 4 + ft) * 64 + lane) * 8);
            acc2[ft] = __builtin_amdgcn_mfma_f32_16x16x32_bf16(wfr, df, acc2[ft], 0, 0, 0);
        }
    }

    // ---- residual update ----
    #pragma unroll
    for (int ft = 0; ft < 4; ++ft) {
        float* hp = h + (size_t)n16 * 64 + ft * 16 + mrow0;
        float4 hv = *(const float4*)hp;
        hv.x += acc2[ft][0]; hv.y += acc2[ft][1]; hv.z += acc2[ft][2]; hv.w += acc2[ft][3];
        *(float4*)hp = hv;
        bf16x4 hb = {(bf16_t)hv.x, (bf16_t)hv.y, (bf16_t)hv.z, (bf16_t)hv.w};
        *(bf16x4*)(hB + (size_t)n16 * 64 + ft * 16 + mrow0) = hb;
    }
    if (kgrp < 3) {
        if (n16 < N_LIG) x4[n16 * 4 + kgrp] += coord[n16 * 3 + kgrp];
        coord[n16 * 3 + kgrp] = 0.0f;   // self-clear for next layer
    }
}

// ---------------- output head ----------------
__global__ void k_out(const float* __restrict__ h, const float* __restrict__ x4,
                      const float* __restrict__ lig_x,
                      const float* __restrict__ oW1, const float* __restrict__ ob1,
                      const float* __restrict__ oW2, const float* __restrict__ ob2,
                      float* __restrict__ out) {
    int gid = blockIdx.x * blockDim.x + threadIdx.x;
    int n = gid >> 6;
    int lane = gid & 63;
    if (n >= N_LIG) return;
    float hv = h[n * 64 + lane];
    float a = ob1[lane];
    #pragma unroll
    for (int k = 0; k < 64; ++k) a = fmaf(__shfl(hv, k, 64), oW1[k * 64 + lane], a);
    float p = silu_f(a) * oW2[lane];
    #pragma unroll
    for (int off = 32; off > 0; off >>= 1) p += __shfl_xor(p, off, 64);
    float scale = p + ob2[0];
    if (lane < 3) out[n * 3 + lane] = scale * (x4[n * 4 + lane] - lig_x[n * 3 + lane]);
}

// ---------------- launch ----------------
extern "C" void kernel_launch(void* const* d_in, const int* in_sizes, int n_in,
                              void* d_out, int out_size, void* d_ws, size_t ws_size,
                              hipStream_t stream) {
    const float* lig_x      = (const float*)d_in[0];
    const float* lig_h      = (const float*)d_in[1];
    const float* poc_x      = (const float*)d_in[2];
    const float* poc_h      = (const float*)d_in[3];
    const int*   lig_ei     = (const int*)d_in[4];
    const float* lig_attr   = (const float*)d_in[5];
    const int*   poc_ei     = (const int*)d_in[6];
    const float* poc_attr   = (const float*)d_in[7];
    const int*   cross_ei   = (const int*)d_in[8];
    const float* cross_attr = (const float*)d_in[9];
    const float* t          = (const float*)d_in[10];
    const float* lig_emb_W  = (const float*)d_in[11];
    const float* lig_emb_b  = (const float*)d_in[12];
    const float* poc_emb_W  = (const float*)d_in[13];
    const float* poc_emb_b  = (const float*)d_in[14];
    const float* lig_ee_W   = (const float*)d_in[15];
    const float* lig_ee_b   = (const float*)d_in[16];
    const float* poc_ee_W   = (const float*)d_in[17];
    const float* poc_ee_b   = (const float*)d_in[18];
    const float* cross_ee_W = (const float*)d_in[19];
    const float* cross_ee_b = (const float*)d_in[20];
    const float* phi_e_W1   = (const float*)d_in[21];
    const float* phi_e_b1   = (const float*)d_in[22];
    const float* phi_e_W2   = (const float*)d_in[23];
    const float* phi_e_b2   = (const float*)d_in[24];
    const float* phi_x_W1   = (const float*)d_in[25];
    const float* phi_x_b1   = (const float*)d_in[26];
    const float* phi_x_W2   = (const float*)d_in[27];
    const float* phi_x_b2   = (const float*)d_in[28];
    const float* phi_h_W1   = (const float*)d_in[29];
    const float* phi_h_b1   = (const float*)d_in[30];
    const float* phi_h_W2   = (const float*)d_in[31];
    const float* phi_h_b2   = (const float*)d_in[32];
    const float* out_W1     = (const float*)d_in[33];
    const float* out_b1     = (const float*)d_in[34];
    const float* out_W2     = (const float*)d_in[35];
    const float* out_b2     = (const float*)d_in[36];

    // ---- workspace carve (256B aligned chunks) ----
    char* p = (char*)d_ws;
    auto carve = [&](size_t bytes) { char* r = p; p += (bytes + 255) & ~(size_t)255; return r; };
    float*  h      = (float*)carve((size_t)N_TOT * 64 * 4);
    bf16_t* hB     = (bf16_t*)carve((size_t)N_TOT * 64 * 2);
    bf16_t* msgB   = (bf16_t*)carve((size_t)N_TOT * 64 * 2);
    float*  x4     = (float*)carve((size_t)N_TOT * 4 * 4);
    float*  coord  = (float*)carve((size_t)N_TOT * 3 * 4);
    bf16_t* WhP    = (bf16_t*)carve((size_t)4 * 24 * 512 * 2);
    float*  beff   = (float*)carve((size_t)12 * 64 * 4);
    bf16_t* Bg1    = (bf16_t*)carve((size_t)12 * 5 * 4 * 512 * 2);
    bf16_t* Bg23   = (bf16_t*)carve((size_t)4 * 16 * 512 * 2);
    bf16_t* attrF  = (bf16_t*)carve((size_t)E_TOT * 16 * 2);
    int*    srcA   = (int*)carve((size_t)E_TOT * 4);
    int*    dstA   = (int*)carve((size_t)E_TOT * 4);
    int*    sortedPos = (int*)carve((size_t)E_TOT * 4);
    int*    cnt    = (int*)carve((size_t)N_TOT * 4);
    int*    cursor = (int*)carve((size_t)N_TOT * 4);
    int*    rowptr = (int*)carve((size_t)(N_TOT + 1) * 4);
    bf16_t* mBuf   = (bf16_t*)carve((size_t)E_TOT * 64 * 2);

    // ---- setup (once per launch) ----
    hipMemsetAsync(cnt, 0, (size_t)N_TOT * 4, stream);
    hipMemsetAsync(coord, 0, (size_t)N_TOT * 3 * 4, stream);  // layer 0; k_node self-clears after
    k_build_edges<<<E_TOT / 256, 256, 0, stream>>>(
        lig_ei, poc_ei, cross_ei, lig_attr, poc_attr, cross_attr, srcA, dstA, cnt, attrF);
    k_scan<<<1, 1024, 0, stream>>>(cnt, rowptr, cursor);
    k_scatter<<<E_TOT / 256, 256, 0, stream>>>(dstA, cursor, sortedPos);
    k_pack_all<<<(PK_TOT + 255) / 256, 256, 0, stream>>>(
        phi_e_W1, phi_e_b1, lig_ee_W, lig_ee_b, poc_ee_W, poc_ee_b, cross_ee_W, cross_ee_b,
        phi_e_W2, phi_x_W1, phi_h_W1, phi_h_W2, Bg1, Bg23, WhP, beff);
    k_embed<<<(N_TOT * 64) / 256, 256, 0, stream>>>(
        lig_x, lig_h, poc_x, poc_h, t, lig_emb_W, lig_emb_b, poc_emb_W, poc_emb_b, h, hB, x4);

    // ---- layers ----
    for (int l = 0; l < 4; ++l) {
        k_edge_mfma<<<E_TOT / 128, 256, 0, stream>>>(
            hB, x4, srcA, dstA, sortedPos, attrF,
            Bg1 + (size_t)l * 3 * 5 * 4 * 512, beff + (size_t)l * 3 * 64,
            Bg23 + (size_t)l * 16 * 512,
            phi_e_b2 + l * 64, phi_x_b1 + l * 64,
            phi_x_W2 + l * 64, phi_x_b2 + l,
            mBuf, coord);
        k_gather<<<N_TOT / 16, 256, 0, stream>>>(mBuf, rowptr, msgB);
        k_node<<<N_TOT / 64, 256, 0, stream>>>(
            h, hB, x4, msgB, coord,
            WhP + (size_t)l * 24 * 512,
            phi_h_b1 + l * 64, phi_h_b2 + l * 64);
    }

    k_out<<<(N_LIG * 64) / 256, 256, 0, stream>>>(
        h, x4, lig_x, out_W1, out_b1, out_W2, out_b2, (float*)d_out);
}

// Round 11
// 710.447 us; speedup vs baseline: 1.5511x; 1.5511x over previous
//
#include <hip/hip_runtime.h>

#define N_LIG 16384
#define M_POC 32768
#define N_TOT (N_LIG + M_POC)           // 49152
#define E_LIG 163840
#define E_POC 327680
#define E_CROSS (N_LIG * 8)             // 131072
#define E_TOT (E_LIG + E_POC + E_CROSS) // 622592
#define TE 16                           // nodes per wave tile (k_node)

typedef __bf16 bf16_t;
typedef bf16_t bf16x8 __attribute__((ext_vector_type(8)));
typedef bf16_t bf16x4 __attribute__((ext_vector_type(4)));
typedef float f32x4 __attribute__((ext_vector_type(4)));

// k_edge LDS: ONE wave-private mT buffer (32 edge rows, stride 72 bf16)
#define SM 72
#define EDGE_WAVE_BYTES (32 * SM * 2)   // 4608 B/wave -> 18432 B/block

// fast transcendentals (v_rcp_f32; rel err ~1e-7 << bf16 rounding)
__device__ __forceinline__ float fast_rcp(float x) { return __builtin_amdgcn_rcpf(x); }
__device__ __forceinline__ float silu_f(float v) {
    return v * fast_rcp(1.0f + __expf(-v));
}
__device__ __forceinline__ float tanh_f(float v) {
    float a = fabsf(v);
    float t = __expf(-2.0f * a);
    float r = (1.0f - t) * fast_rcp(1.0f + t);
    return copysignf(r, v);
}

__device__ __forceinline__ void atomic_add_f32(float* p, float v) {
    __hip_atomic_fetch_add(p, v, __ATOMIC_RELAXED, __HIP_MEMORY_SCOPE_AGENT);
}

// wave-level LDS fence (all LDS regions are wave-private)
__device__ __forceinline__ void lds_fence() {
    asm volatile("s_waitcnt lgkmcnt(0)" ::: "memory");
}

// ---------------- setup kernels ----------------

// builds src/dst, histograms dst, AND packs attr fragments (one pass over edges)
__global__ void k_build_edges(const int* __restrict__ lig_ei, const int* __restrict__ poc_ei,
                              const int* __restrict__ cross_ei,
                              const float* __restrict__ lig_attr, const float* __restrict__ poc_attr,
                              const float* __restrict__ cross_attr,
                              int* __restrict__ srcA, int* __restrict__ dstA,
                              int* __restrict__ cnt, bf16_t* __restrict__ attrF) {
    int e = blockIdx.x * blockDim.x + threadIdx.x;
    if (e >= E_TOT) return;
    int s, d;
    const float* a; int K;
    if (e < E_LIG) {
        s = lig_ei[e];
        d = lig_ei[E_LIG + e];
        a = lig_attr + (size_t)e * 6; K = 6;
    } else if (e < E_LIG + E_POC) {
        int i = e - E_LIG;
        s = poc_ei[i] + N_LIG;
        d = poc_ei[E_POC + i] + N_LIG;
        a = poc_attr + (size_t)i * 16; K = 16;
    } else {
        int i = e - E_LIG - E_POC;
        s = cross_ei[i] + N_LIG;
        d = cross_ei[E_CROSS + i];
        a = cross_attr + (size_t)i * 16; K = 16;
    }
    srcA[e] = s;
    dstA[e] = d;
    atomicAdd(&cnt[d], 1);
    bf16_t* o = attrF + (size_t)e * 16;
    #pragma unroll
    for (int k = 0; k < 16; ++k) o[k] = (bf16_t)((k < K) ? a[k] : 0.0f);
}

// single block, 1024 threads, 48 bins per thread
__global__ __launch_bounds__(1024) void k_scan(const int* __restrict__ cnt,
                                               int* __restrict__ rowptr,
                                               int* __restrict__ cursor) {
    __shared__ int sums[1024];
    int tid = threadIdx.x;
    int local[48];
    int s = 0;
    for (int i = 0; i < 48; ++i) { local[i] = s; s += cnt[tid * 48 + i]; }
    sums[tid] = s;
    __syncthreads();
    for (int off = 1; off < 1024; off <<= 1) {
        int v = (tid >= off) ? sums[tid - off] : 0;
        __syncthreads();
        sums[tid] += v;
        __syncthreads();
    }
    int base = (tid == 0) ? 0 : sums[tid - 1];
    for (int i = 0; i < 48; ++i) {
        int v = base + local[i];
        int idx = tid * 48 + i;
        rowptr[idx] = v;
        cursor[idx] = v;
    }
    if (tid == 1023) rowptr[N_TOT] = sums[1023];
}

__global__ void k_scatter(const int* __restrict__ dstA, int* __restrict__ cursor,
                          int* __restrict__ sortedPos) {
    int e = blockIdx.x * blockDim.x + threadIdx.x;
    if (e < E_TOT) sortedPos[e] = atomicAdd(&cursor[dstA[e]], 1);
}

// ---- fused weight prep ----
// Fragment mapping (weights-as-A): frag[lane][j] = W[kbase+(lane>>4)*8+j][ft*16+(lane&15)]
// GEMM1 k-layout: 0..63 h_src, 64..127 h_dst, 128..143 folded attr, 144 dist, 145..159 zero.
#define PK_G1   (12 * 5 * 4 * 64)                     // 15360
#define PK_G23  (4 * 4 * 4 * 64)                      // 4096
#define PK_WH   (4 * 24 * 64)                         // 6144
#define PK_BEFF (12 * 64)                             // 768
#define PK_TOT  (PK_G1 + PK_G23 + PK_WH + PK_BEFF)    // 26368

__global__ void k_pack_all(const float* __restrict__ phi_e_W1, const float* __restrict__ phi_e_b1,
                           const float* __restrict__ lig_ee_W, const float* __restrict__ lig_ee_b,
                           const float* __restrict__ poc_ee_W, const float* __restrict__ poc_ee_b,
                           const float* __restrict__ cross_ee_W, const float* __restrict__ cross_ee_b,
                           const float* __restrict__ phi_e_W2, const float* __restrict__ phi_x_W1,
                           const float* __restrict__ phi_h_W1, const float* __restrict__ phi_h_W2,
                           bf16_t* __restrict__ Bg1, bf16_t* __restrict__ Bg23,
                           bf16_t* __restrict__ WhP, float* __restrict__ beff) {
    int tid = blockIdx.x * blockDim.x + threadIdx.x;
    if (tid < PK_G1) {
        int lt = tid / 1280;
        int rem = tid - lt * 1280;
        int c = rem >> 8;
        int ft = (rem >> 6) & 3;
        int lane = rem & 63;
        int l = lt / 3, t = lt % 3;
        const float* W1l = phi_e_W1 + l * 193 * 64;
        const float* We; int K;
        if (t == 0) { We = lig_ee_W; K = 6; }
        else if (t == 1) { We = poc_ee_W; K = 16; }
        else { We = cross_ee_W; K = 16; }
        int col = ft * 16 + (lane & 15);
        int k0 = c * 32 + (lane >> 4) * 8;
        #pragma unroll
        for (int j = 0; j < 8; ++j) {
            int row = k0 + j;
            float v = 0.0f;
            if (row < 128) v = W1l[row * 64 + col];
            else if (row < 144) {
                int kk = row - 128;
                if (kk < K) {
                    float a = 0.0f;
                    for (int q = 0; q < 64; ++q) a = fmaf(We[kk * 64 + q], W1l[(129 + q) * 64 + col], a);
                    v = a;
                }
            } else if (row == 144) {
                v = W1l[128 * 64 + col];   // dist row
            }
            Bg1[(size_t)tid * 8 + j] = (bf16_t)v;
        }
    } else if (tid < PK_G1 + PK_G23) {
        int u = tid - PK_G1;
        int lane = u & 63;
        int ft = (u >> 6) & 3;
        int c = (u >> 8) & 3;
        int l = u >> 10;
        const float* W = (c < 2) ? (phi_e_W2 + l * 4096) : (phi_x_W1 + l * 4096);
        int kb = (c & 1) * 32;
        int col = ft * 16 + (lane & 15);
        int k0 = kb + (lane >> 4) * 8;
        #pragma unroll
        for (int j = 0; j < 8; ++j)
            Bg23[(size_t)u * 8 + j] = (bf16_t)W[(k0 + j) * 64 + col];
    } else if (tid < PK_G1 + PK_G23 + PK_WH) {
        int u = tid - PK_G1 - PK_G23;
        int lane = u & 63;
        int frag = (u >> 6) % 24;
        int l = (u >> 6) / 24;
        const float* W; int kc, ft;
        if (frag < 16) { W = phi_h_W1 + l * 128 * 64; kc = frag >> 2; ft = frag & 3; }
        else           { W = phi_h_W2 + l * 64 * 64;  kc = (frag - 16) >> 2; ft = (frag - 16) & 3; }
        int col = ft * 16 + (lane & 15);
        int k0 = kc * 32 + (lane >> 4) * 8;
        #pragma unroll
        for (int j = 0; j < 8; ++j)
            WhP[(size_t)u * 8 + j] = (bf16_t)W[(k0 + j) * 64 + col];
    } else if (tid < PK_TOT) {
        int u = tid - PK_G1 - PK_G23 - PK_WH;
        int j = u & 63;
        int lt = u >> 6;
        int l = lt / 3, t = lt % 3;
        const float* W1l = phi_e_W1 + l * 193 * 64;
        const float* Be = (t == 0) ? lig_ee_b : ((t == 1) ? poc_ee_b : cross_ee_b);
        float v = phi_e_b1[l * 64 + j];
        for (int q = 0; q < 64; ++q) v = fmaf(Be[q], W1l[(129 + q) * 64 + j], v);
        beff[u] = v;
    }
}

__global__ void k_embed(const float* __restrict__ lig_x, const float* __restrict__ lig_h,
                        const float* __restrict__ poc_x, const float* __restrict__ poc_h,
                        const float* __restrict__ t,
                        const float* __restrict__ ligW, const float* __restrict__ ligB,
                        const float* __restrict__ pocW, const float* __restrict__ pocB,
                        float* __restrict__ h, bf16_t* __restrict__ hB, float* __restrict__ x4) {
    int gid = blockIdx.x * blockDim.x + threadIdx.x;
    int n = gid >> 6;
    int lane = gid & 63;
    if (n >= N_TOT) return;
    float a;
    if (n < N_LIG) {
        a = ligB[lane];
        #pragma unroll
        for (int k = 0; k < 17; ++k) a = fmaf(lig_h[n * 17 + k], ligW[k * 64 + lane], a);
        a = fmaf(t[0], ligW[17 * 64 + lane], a);
        if (lane < 4) x4[n * 4 + lane] = (lane < 3) ? lig_x[n * 3 + lane] : 0.0f;
    } else {
        int p = n - N_LIG;
        a = pocB[lane];
        #pragma unroll
        for (int k = 0; k < 29; ++k) a = fmaf(poc_h[p * 29 + k], pocW[k * 64 + lane], a);
        if (lane < 4) x4[n * 4 + lane] = (lane < 3) ? poc_x[p * 3 + lane] : 0.0f;
    }
    h[n * 64 + lane] = a;
    hB[n * 64 + lane] = (bf16_t)a;
}

// ---------------- per-layer MFMA edge kernel: 32 edges/wave, register extras ----------------
// __launch_bounds__(256,4): true per-wave register demand is ~108 (60 arch VGPR reported
// + ~48 acc regs in the unified file). Forcing more waves/EU caps the allocator and
// spills to scratch (R10: FETCH 63->284 MB, WRITE 89->441 MB, k_edge 82->177 us).
__global__ __launch_bounds__(256, 4) void k_edge_mfma(
    const bf16_t* __restrict__ hB, const float* __restrict__ x4,
    const int* __restrict__ srcA, const int* __restrict__ dstA,
    const int* __restrict__ sortedPos,
    const bf16_t* __restrict__ attrF,
    const bf16_t* __restrict__ Bg1L,   // + t*5*4*512 inside
    const float* __restrict__ beffL,   // + t*64 inside
    const bf16_t* __restrict__ Bg23L,
    const float* __restrict__ b2, const float* __restrict__ bx1,
    const float* __restrict__ Wx2, const float* __restrict__ bx2,
    bf16_t* __restrict__ mBuf, float* __restrict__ coord_agg) {
    __shared__ __align__(16) char lds[4 * EDGE_WAVE_BYTES];
    const int lane = threadIdx.x & 63;
    const int wave = threadIdx.x >> 6;
    bf16_t* mT = (bf16_t*)(lds + wave * EDGE_WAVE_BYTES);
    const int base = (blockIdx.x * 4 + wave) * 32;

    // edge type (tile-uniform) — only selects weight pack
    int tt;
    if (base < E_LIG) tt = 0;
    else if (base < E_LIG + E_POC) tt = 1;
    else tt = 2;

    const int edge = lane & 15;
    const int kgrp = lane >> 4;
    const int mrow0 = kgrp * 4;
    const int e0 = base + edge;
    const int e1 = base + 16 + edge;
    const int sv0 = srcA[e0], sv1 = srcA[e1];
    const int dv0 = dstA[e0], dv1 = dstA[e1];
    const int sp0 = sortedPos[e0], sp1 = sortedPos[e1];

    // ---- h B-fragments: 8 direct 16B gathers (layout-exact, all independent) ----
    bf16x8 hs0a = *(const bf16x8*)(hB + (size_t)sv0 * 64 + kgrp * 8);
    bf16x8 hs0b = *(const bf16x8*)(hB + (size_t)sv0 * 64 + 32 + kgrp * 8);
    bf16x8 hd0a = *(const bf16x8*)(hB + (size_t)dv0 * 64 + kgrp * 8);
    bf16x8 hd0b = *(const bf16x8*)(hB + (size_t)dv0 * 64 + 32 + kgrp * 8);
    bf16x8 hs1a = *(const bf16x8*)(hB + (size_t)sv1 * 64 + kgrp * 8);
    bf16x8 hs1b = *(const bf16x8*)(hB + (size_t)sv1 * 64 + 32 + kgrp * 8);
    bf16x8 hd1a = *(const bf16x8*)(hB + (size_t)dv1 * 64 + kgrp * 8);
    bf16x8 hd1b = *(const bf16x8*)(hB + (size_t)dv1 * 64 + 32 + kgrp * 8);

    // ---- extras B-fragments (k 128..159): prepacked attr (kgrp<2) + dist (kgrp==2) ----
    const bf16_t Z = (bf16_t)0.0f;
    bf16x8 ex0 = {Z, Z, Z, Z, Z, Z, Z, Z};
    bf16x8 ex1 = {Z, Z, Z, Z, Z, Z, Z, Z};
    float d0s0 = 0.f, d1s0 = 0.f, d2s0 = 0.f;   // diffs (held on kgrp==2 lanes)
    float d0s1 = 0.f, d1s1 = 0.f, d2s1 = 0.f;
    if (kgrp < 2) {
        ex0 = *(const bf16x8*)(attrF + (size_t)e0 * 16 + kgrp * 8);
        ex1 = *(const bf16x8*)(attrF + (size_t)e1 * 16 + kgrp * 8);
    } else if (kgrp == 2) {
        float4 xs0 = *(const float4*)(x4 + (size_t)sv0 * 4);
        float4 xd0 = *(const float4*)(x4 + (size_t)dv0 * 4);
        float4 xs1 = *(const float4*)(x4 + (size_t)sv1 * 4);
        float4 xd1 = *(const float4*)(x4 + (size_t)dv1 * 4);
        d0s0 = xs0.x - xd0.x; d1s0 = xs0.y - xd0.y; d2s0 = xs0.z - xd0.z;
        d0s1 = xs1.x - xd1.x; d1s1 = xs1.y - xd1.y; d2s1 = xs1.z - xd1.z;
        float dist0 = (d0s0 * d0s0 + d1s0 * d1s0 + d2s0 * d2s0) * 0.01f;
        float dist1 = (d0s1 * d0s1 + d1s1 * d1s1 + d2s1 * d2s1) * 0.01f;
        ex0[0] = (bf16_t)dist0;
        ex1[0] = (bf16_t)dist1;
    }

    // ---- GEMM1: 5 kc x 4 ft x 2 sub-tiles (each weight frag feeds 2 MFMAs) ----
    const bf16_t* Bg1 = Bg1L + (size_t)tt * 5 * 4 * 512;
    const float* beff = beffL + tt * 64;
    f32x4 acc0[4], acc1[4];
    #pragma unroll
    for (int ft = 0; ft < 4; ++ft) {
        float4 bv = *(const float4*)(beff + ft * 16 + mrow0);
        acc0[ft] = (f32x4){bv.x, bv.y, bv.z, bv.w};
        acc1[ft] = acc0[ft];
    }
    bf16x8 bdat0[5] = {hs0a, hs0b, hd0a, hd0b, ex0};
    bf16x8 bdat1[5] = {hs1a, hs1b, hd1a, hd1b, ex1};
    #pragma unroll
    for (int c = 0; c < 5; ++c) {
        #pragma unroll
        for (int ft = 0; ft < 4; ++ft) {
            bf16x8 wfr = *(const bf16x8*)(Bg1 + ((size_t)(c * 4 + ft) * 64 + lane) * 8);
            acc0[ft] = __builtin_amdgcn_mfma_f32_16x16x32_bf16(wfr, bdat0[c], acc0[ft], 0, 0, 0);
            acc1[ft] = __builtin_amdgcn_mfma_f32_16x16x32_bf16(wfr, bdat1[c], acc1[ft], 0, 0, 0);
        }
    }
    // epilogue: lane's 4 accs = 4 consecutive feats of its edge -> packed b64 writes
    #pragma unroll
    for (int ft = 0; ft < 4; ++ft) {
        bf16x4 v0 = {(bf16_t)silu_f(acc0[ft][0]), (bf16_t)silu_f(acc0[ft][1]),
                     (bf16_t)silu_f(acc0[ft][2]), (bf16_t)silu_f(acc0[ft][3])};
        bf16x4 v1 = {(bf16_t)silu_f(acc1[ft][0]), (bf16_t)silu_f(acc1[ft][1]),
                     (bf16_t)silu_f(acc1[ft][2]), (bf16_t)silu_f(acc1[ft][3])};
        *(bf16x4*)(mT + edge * SM + ft * 16 + mrow0) = v0;
        *(bf16x4*)(mT + (16 + edge) * SM + ft * 16 + mrow0) = v1;
    }
    lds_fence();

    // ---- GEMM2: m = silu(m1 @ W2 + b2) ----
    f32x4 acc20[4], acc21[4];
    #pragma unroll
    for (int ft = 0; ft < 4; ++ft) {
        float4 bv = *(const float4*)(b2 + ft * 16 + mrow0);
        acc20[ft] = (f32x4){bv.x, bv.y, bv.z, bv.w};
        acc21[ft] = acc20[ft];
    }
    bf16x8 m10[2], m11[2];
    #pragma unroll
    for (int c = 0; c < 2; ++c) {
        m10[c] = *(const bf16x8*)(mT + edge * SM + c * 32 + kgrp * 8);
        m11[c] = *(const bf16x8*)(mT + (16 + edge) * SM + c * 32 + kgrp * 8);
    }
    #pragma unroll
    for (int c = 0; c < 2; ++c) {
        #pragma unroll
        for (int ft = 0; ft < 4; ++ft) {
            bf16x8 wfr = *(const bf16x8*)(Bg23L + ((size_t)(c * 4 + ft) * 64 + lane) * 8);
            acc20[ft] = __builtin_amdgcn_mfma_f32_16x16x32_bf16(wfr, m10[c], acc20[ft], 0, 0, 0);
            acc21[ft] = __builtin_amdgcn_mfma_f32_16x16x32_bf16(wfr, m11[c], acc21[ft], 0, 0, 0);
        }
    }
    lds_fence();   // m1 reads drained before overwrite
    #pragma unroll
    for (int ft = 0; ft < 4; ++ft) {
        bf16x4 v0 = {(bf16_t)silu_f(acc20[ft][0]), (bf16_t)silu_f(acc20[ft][1]),
                     (bf16_t)silu_f(acc20[ft][2]), (bf16_t)silu_f(acc20[ft][3])};
        bf16x4 v1 = {(bf16_t)silu_f(acc21[ft][0]), (bf16_t)silu_f(acc21[ft][1]),
                     (bf16_t)silu_f(acc21[ft][2]), (bf16_t)silu_f(acc21[ft][3])};
        *(bf16x4*)(mT + edge * SM + ft * 16 + mrow0) = v0;
        *(bf16x4*)(mT + (16 + edge) * SM + ft * 16 + mrow0) = v1;
    }
    lds_fence();

    // ---- GEMM3 B-frags from LDS; the same reads feed the mBuf store (b128 x4) ----
    bf16x8 g0[2], g1[2];
    #pragma unroll
    for (int c = 0; c < 2; ++c) {
        g0[c] = *(const bf16x8*)(mT + edge * SM + c * 32 + kgrp * 8);
        g1[c] = *(const bf16x8*)(mT + (16 + edge) * SM + c * 32 + kgrp * 8);
        *(bf16x8*)(mBuf + (size_t)sp0 * 64 + c * 32 + kgrp * 8) = g0[c];
        *(bf16x8*)(mBuf + (size_t)sp1 * 64 + c * 32 + kgrp * 8) = g1[c];
    }

    f32x4 acc30[4], acc31[4];
    #pragma unroll
    for (int ft = 0; ft < 4; ++ft) {
        float4 bv = *(const float4*)(bx1 + ft * 16 + mrow0);
        acc30[ft] = (f32x4){bv.x, bv.y, bv.z, bv.w};
        acc31[ft] = acc30[ft];
    }
    const bf16_t* Bg3 = Bg23L + (size_t)2 * 4 * 512;
    #pragma unroll
    for (int c = 0; c < 2; ++c) {
        #pragma unroll
        for (int ft = 0; ft < 4; ++ft) {
            bf16x8 wfr = *(const bf16x8*)(Bg3 + ((size_t)(c * 4 + ft) * 64 + lane) * 8);
            acc30[ft] = __builtin_amdgcn_mfma_f32_16x16x32_bf16(wfr, g0[c], acc30[ft], 0, 0, 0);
            acc31[ft] = __builtin_amdgcn_mfma_f32_16x16x32_bf16(wfr, g1[c], acc31[ft], 0, 0, 0);
        }
    }

    // ---- cw = tanh(silu(p) . Wx2 + bx2): per-lane partial, 2-shuffle reduce per sub-tile ----
    float s0 = 0.0f, s1 = 0.0f;
    #pragma unroll
    for (int ft = 0; ft < 4; ++ft) {
        float4 wv = *(const float4*)(Wx2 + ft * 16 + mrow0);
        s0 = fmaf(silu_f(acc30[ft][0]), wv.x, s0);
        s0 = fmaf(silu_f(acc30[ft][1]), wv.y, s0);
        s0 = fmaf(silu_f(acc30[ft][2]), wv.z, s0);
        s0 = fmaf(silu_f(acc30[ft][3]), wv.w, s0);
        s1 = fmaf(silu_f(acc31[ft][0]), wv.x, s1);
        s1 = fmaf(silu_f(acc31[ft][1]), wv.y, s1);
        s1 = fmaf(silu_f(acc31[ft][2]), wv.z, s1);
        s1 = fmaf(silu_f(acc31[ft][3]), wv.w, s1);
    }
    s0 += __shfl_xor(s0, 16, 64); s0 += __shfl_xor(s0, 32, 64);
    s1 += __shfl_xor(s1, 16, 64); s1 += __shfl_xor(s1, 32, 64);
    const float bx2v = bx2[0];
    const float cw0 = tanh_f(s0 + bx2v);
    const float cw1 = tanh_f(s1 + bx2v);

    // diffs live on kgrp==2 lanes (lane 32+edge); 3 shuffles per sub-tile + select
    float a0 = __shfl(d0s0, 32 + edge, 64);
    float a1 = __shfl(d1s0, 32 + edge, 64);
    float a2 = __shfl(d2s0, 32 + edge, 64);
    float b0 = __shfl(d0s1, 32 + edge, 64);
    float b1 = __shfl(d1s1, 32 + edge, 64);
    float b2v_ = __shfl(d2s1, 32 + edge, 64);
    if (kgrp < 3) {
        float dsel0 = (kgrp == 0) ? a0 : ((kgrp == 1) ? a1 : a2);
        float dsel1 = (kgrp == 0) ? b0 : ((kgrp == 1) ? b1 : b2v_);
        if (dv0 < N_LIG) atomic_add_f32(&coord_agg[dv0 * 3 + kgrp], dsel0 * cw0);
        if (dv1 < N_LIG) atomic_add_f32(&coord_agg[dv1 * 3 + kgrp], dsel1 * cw1);
    }
}

// ---------------- msg gather kernel: wave = 4 nodes, high occupancy streaming ----------------
__global__ __launch_bounds__(256) void k_gather(
    const bf16_t* __restrict__ mBuf, const int* __restrict__ rowptr,
    bf16_t* __restrict__ msgB) {
    const int lane = threadIdx.x & 63;
    const int wave = threadIdx.x >> 6;
    const int fq = lane & 15;        // feature quad
    const int sub = lane >> 4;       // 4-way edge parallelism
    const int nbase = (blockIdx.x * 4 + wave) * 4;
    #pragma unroll
    for (int r = 0; r < 4; ++r) {
        const int n = nbase + r;
        const int s0 = rowptr[n];
        const int s1 = rowptr[n + 1];
        float a0 = 0.f, a1 = 0.f, a2 = 0.f, a3 = 0.f;
        for (int i = s0 + sub; i < s1; i += 4) {
            bf16x4 v = *(const bf16x4*)(mBuf + (size_t)i * 64 + fq * 4);
            a0 += (float)v[0]; a1 += (float)v[1]; a2 += (float)v[2]; a3 += (float)v[3];
        }
        a0 += __shfl_xor(a0, 16, 64); a1 += __shfl_xor(a1, 16, 64);
        a2 += __shfl_xor(a2, 16, 64); a3 += __shfl_xor(a3, 16, 64);
        a0 += __shfl_xor(a0, 32, 64); a1 += __shfl_xor(a1, 32, 64);
        a2 += __shfl_xor(a2, 32, 64); a3 += __shfl_xor(a3, 32, 64);
        if (lane < 16) {
            bf16x4 v = {(bf16_t)a0, (bf16_t)a1, (bf16_t)a2, (bf16_t)a3};
            *(bf16x4*)(msgB + (size_t)n * 64 + fq * 4) = v;
        }
    }
}

// ---------------- per-layer node update: MLP only (msgB already gathered) ----------------
#define NODE_WAVE_BYTES 2304   // mid, stride 72
__global__ __launch_bounds__(256) void k_node(
    float* __restrict__ h, bf16_t* __restrict__ hB, float* __restrict__ x4,
    const bf16_t* __restrict__ msgB,
    float* __restrict__ coord,
    const bf16_t* __restrict__ WhL,   // 24 frags: 0..15 Wh1 (kc*4+ft), 16..23 Wh2
    const float* __restrict__ bh1, const float* __restrict__ bh2) {
    __shared__ __align__(16) char lds[4 * NODE_WAVE_BYTES];
    const int lane = threadIdx.x & 63;
    const int wave = threadIdx.x >> 6;
    bf16_t* mid = (bf16_t*)(lds + wave * NODE_WAVE_BYTES);
    const int base = (blockIdx.x * 4 + wave) * TE;

    const int node = lane & 15;
    const int kgrp = lane >> 4;
    const int mrow0 = kgrp * 4;
    const int n16 = base + node;

    // ---- GEMM1: D[feat][node] = Wh1^T . [h|msg]^T + bh1 : 4 kc x 4 ft ----
    f32x4 acc[4];
    #pragma unroll
    for (int ft = 0; ft < 4; ++ft) {
        float4 bv = *(const float4*)(bh1 + ft * 16 + mrow0);
        acc[ft] = (f32x4){bv.x, bv.y, bv.z, bv.w};
    }
    bf16x8 d0 = *(const bf16x8*)(hB + (size_t)n16 * 64 + kgrp * 8);
    bf16x8 d1 = *(const bf16x8*)(hB + (size_t)n16 * 64 + 32 + kgrp * 8);
    bf16x8 d2 = *(const bf16x8*)(msgB + (size_t)n16 * 64 + kgrp * 8);
    bf16x8 d3 = *(const bf16x8*)(msgB + (size_t)n16 * 64 + 32 + kgrp * 8);
    bf16x8 bdat[4] = {d0, d1, d2, d3};
    #pragma unroll
    for (int c = 0; c < 4; ++c) {
        #pragma unroll
        for (int ft = 0; ft < 4; ++ft) {
            bf16x8 wfr = *(const bf16x8*)(WhL + ((size_t)(c * 4 + ft) * 64 + lane) * 8);
            acc[ft] = __builtin_amdgcn_mfma_f32_16x16x32_bf16(wfr, bdat[c], acc[ft], 0, 0, 0);
        }
    }
    #pragma unroll
    for (int ft = 0; ft < 4; ++ft) {
        bf16x4 v = {(bf16_t)silu_f(acc[ft][0]), (bf16_t)silu_f(acc[ft][1]),
                    (bf16_t)silu_f(acc[ft][2]), (bf16_t)silu_f(acc[ft][3])};
        *(bf16x4*)(mid + node * SM + ft * 16 + mrow0) = v;
    }
    lds_fence();

    // ---- GEMM2: 2 kc x 4 ft ----
    f32x4 acc2[4];
    #pragma unroll
    for (int ft = 0; ft < 4; ++ft) {
        float4 bv = *(const float4*)(bh2 + ft * 16 + mrow0);
        acc2[ft] = (f32x4){bv.x, bv.y, bv.z, bv.w};
    }
    bf16x8 g0 = *(const bf16x8*)(mid + node * SM + kgrp * 8);
    bf16x8 g1 = *(const bf16x8*)(mid + node * SM + 32 + kgrp * 8);
    #pragma unroll
    for (int c = 0; c < 2; ++c) {
        bf16x8 df = (c == 0) ? g0 : g1;
        #pragma unroll
        for (int ft = 0; ft < 4; ++ft) {
            bf16x8 wfr = *(const bf16x8*)(WhL + ((size_t)(16 + c * 4 + ft) * 64 + lane) * 8);
            acc2[ft] = __builtin_amdgcn_mfma_f32_16x16x32_bf16(wfr, df, acc2[ft], 0, 0, 0);
        }
    }

    // ---- residual update ----
    #pragma unroll
    for (int ft = 0; ft < 4; ++ft) {
        float* hp = h + (size_t)n16 * 64 + ft * 16 + mrow0;
        float4 hv = *(const float4*)hp;
        hv.x += acc2[ft][0]; hv.y += acc2[ft][1]; hv.z += acc2[ft][2]; hv.w += acc2[ft][3];
        *(float4*)hp = hv;
        bf16x4 hb = {(bf16_t)hv.x, (bf16_t)hv.y, (bf16_t)hv.z, (bf16_t)hv.w};
        *(bf16x4*)(hB + (size_t)n16 * 64 + ft * 16 + mrow0) = hb;
    }
    if (kgrp < 3) {
        if (n16 < N_LIG) x4[n16 * 4 + kgrp] += coord[n16 * 3 + kgrp];
        coord[n16 * 3 + kgrp] = 0.0f;   // self-clear for next layer
    }
}

// ---------------- output head ----------------
__global__ void k_out(const float* __restrict__ h, const float* __restrict__ x4,
                      const float* __restrict__ lig_x,
                      const float* __restrict__ oW1, const float* __restrict__ ob1,
                      const float* __restrict__ oW2, const float* __restrict__ ob2,
                      float* __restrict__ out) {
    int gid = blockIdx.x * blockDim.x + threadIdx.x;
    int n = gid >> 6;
    int lane = gid & 63;
    if (n >= N_LIG) return;
    float hv = h[n * 64 + lane];
    float a = ob1[lane];
    #pragma unroll
    for (int k = 0; k < 64; ++k) a = fmaf(__shfl(hv, k, 64), oW1[k * 64 + lane], a);
    float p = silu_f(a) * oW2[lane];
    #pragma unroll
    for (int off = 32; off > 0; off >>= 1) p += __shfl_xor(p, off, 64);
    float scale = p + ob2[0];
    if (lane < 3) out[n * 3 + lane] = scale * (x4[n * 4 + lane] - lig_x[n * 3 + lane]);
}

// ---------------- launch ----------------
extern "C" void kernel_launch(void* const* d_in, const int* in_sizes, int n_in,
                              void* d_out, int out_size, void* d_ws, size_t ws_size,
                              hipStream_t stream) {
    const float* lig_x      = (const float*)d_in[0];
    const float* lig_h      = (const float*)d_in[1];
    const float* poc_x      = (const float*)d_in[2];
    const float* poc_h      = (const float*)d_in[3];
    const int*   lig_ei     = (const int*)d_in[4];
    const float* lig_attr   = (const float*)d_in[5];
    const int*   poc_ei     = (const int*)d_in[6];
    const float* poc_attr   = (const float*)d_in[7];
    const int*   cross_ei   = (const int*)d_in[8];
    const float* cross_attr = (const float*)d_in[9];
    const float* t          = (const float*)d_in[10];
    const float* lig_emb_W  = (const float*)d_in[11];
    const float* lig_emb_b  = (const float*)d_in[12];
    const float* poc_emb_W  = (const float*)d_in[13];
    const float* poc_emb_b  = (const float*)d_in[14];
    const float* lig_ee_W   = (const float*)d_in[15];
    const float* lig_ee_b   = (const float*)d_in[16];
    const float* poc_ee_W   = (const float*)d_in[17];
    const float* poc_ee_b   = (const float*)d_in[18];
    const float* cross_ee_W = (const float*)d_in[19];
    const float* cross_ee_b = (const float*)d_in[20];
    const float* phi_e_W1   = (const float*)d_in[21];
    const float* phi_e_b1   = (const float*)d_in[22];
    const float* phi_e_W2   = (const float*)d_in[23];
    const float* phi_e_b2   = (const float*)d_in[24];
    const float* phi_x_W1   = (const float*)d_in[25];
    const float* phi_x_b1   = (const float*)d_in[26];
    const float* phi_x_W2   = (const float*)d_in[27];
    const float* phi_x_b2   = (const float*)d_in[28];
    const float* phi_h_W1   = (const float*)d_in[29];
    const float* phi_h_b1   = (const float*)d_in[30];
    const float* phi_h_W2   = (const float*)d_in[31];
    const float* phi_h_b2   = (const float*)d_in[32];
    const float* out_W1     = (const float*)d_in[33];
    const float* out_b1     = (const float*)d_in[34];
    const float* out_W2     = (const float*)d_in[35];
    const float* out_b2     = (const float*)d_in[36];

    // ---- workspace carve (256B aligned chunks) ----
    char* p = (char*)d_ws;
    auto carve = [&](size_t bytes) { char* r = p; p += (bytes + 255) & ~(size_t)255; return r; };
    float*  h      = (float*)carve((size_t)N_TOT * 64 * 4);
    bf16_t* hB     = (bf16_t*)carve((size_t)N_TOT * 64 * 2);
    bf16_t* msgB   = (bf16_t*)carve((size_t)N_TOT * 64 * 2);
    float*  x4     = (float*)carve((size_t)N_TOT * 4 * 4);
    float*  coord  = (float*)carve((size_t)N_TOT * 3 * 4);
    bf16_t* WhP    = (bf16_t*)carve((size_t)4 * 24 * 512 * 2);
    float*  beff   = (float*)carve((size_t)12 * 64 * 4);
    bf16_t* Bg1    = (bf16_t*)carve((size_t)12 * 5 * 4 * 512 * 2);
    bf16_t* Bg23   = (bf16_t*)carve((size_t)4 * 16 * 512 * 2);
    bf16_t* attrF  = (bf16_t*)carve((size_t)E_TOT * 16 * 2);
    int*    srcA   = (int*)carve((size_t)E_TOT * 4);
    int*    dstA   = (int*)carve((size_t)E_TOT * 4);
    int*    sortedPos = (int*)carve((size_t)E_TOT * 4);
    int*    cnt    = (int*)carve((size_t)N_TOT * 4);
    int*    cursor = (int*)carve((size_t)N_TOT * 4);
    int*    rowptr = (int*)carve((size_t)(N_TOT + 1) * 4);
    bf16_t* mBuf   = (bf16_t*)carve((size_t)E_TOT * 64 * 2);

    // ---- setup (once per launch) ----
    hipMemsetAsync(cnt, 0, (size_t)N_TOT * 4, stream);
    hipMemsetAsync(coord, 0, (size_t)N_TOT * 3 * 4, stream);  // layer 0; k_node self-clears after
    k_build_edges<<<E_TOT / 256, 256, 0, stream>>>(
        lig_ei, poc_ei, cross_ei, lig_attr, poc_attr, cross_attr, srcA, dstA, cnt, attrF);
    k_scan<<<1, 1024, 0, stream>>>(cnt, rowptr, cursor);
    k_scatter<<<E_TOT / 256, 256, 0, stream>>>(dstA, cursor, sortedPos);
    k_pack_all<<<(PK_TOT + 255) / 256, 256, 0, stream>>>(
        phi_e_W1, phi_e_b1, lig_ee_W, lig_ee_b, poc_ee_W, poc_ee_b, cross_ee_W, cross_ee_b,
        phi_e_W2, phi_x_W1, phi_h_W1, phi_h_W2, Bg1, Bg23, WhP, beff);
    k_embed<<<(N_TOT * 64) / 256, 256, 0, stream>>>(
        lig_x, lig_h, poc_x, poc_h, t, lig_emb_W, lig_emb_b, poc_emb_W, poc_emb_b, h, hB, x4);

    // ---- layers ----
    for (int l = 0; l < 4; ++l) {
        k_edge_mfma<<<E_TOT / 128, 256, 0, stream>>>(
            hB, x4, srcA, dstA, sortedPos, attrF,
            Bg1 + (size_t)l * 3 * 5 * 4 * 512, beff + (size_t)l * 3 * 64,
            Bg23 + (size_t)l * 16 * 512,
            phi_e_b2 + l * 64, phi_x_b1 + l * 64,
            phi_x_W2 + l * 64, phi_x_b2 + l,
            mBuf, coord);
        k_gather<<<N_TOT / 16, 256, 0, stream>>>(mBuf, rowptr, msgB);
        k_node<<<N_TOT / 64, 256, 0, stream>>>(
            h, hB, x4, msgB, coord,
            WhP + (size_t)l * 24 * 512,
            phi_h_b1 + l * 64, phi_h_b2 + l * 64);
    }

    k_out<<<(N_LIG * 64) / 256, 256, 0, stream>>>(
        h, x4, lig_x, out_W1, out_b1, out_W2, out_b2, (float*)d_out);
}